// Round 8
// baseline (518.273 us; speedup 1.0000x reference)
//
#include <hip/hip_runtime.h>

typedef __bf16 bf16x8 __attribute__((ext_vector_type(8)));
typedef float f32x4 __attribute__((ext_vector_type(4)));

constexpr int N_DST0 = 100000, N_DST1 = 20000, N_DST2 = 4096;
constexpr int E0 = 1000000, E1 = 300000, E2 = 61440;
constexpr int NCNT = N_DST0 + N_DST1 + N_DST2;   // 124096
constexpr int ETOT = E0 + E1 + E2;               // 1361440

constexpr int BKT = 256;                          // buckets (g>>9); used 0..242
constexpr int NBKT_USED = (NCNT + 511) / 512;     // 243
constexpr int CAP = 16384;                        // per-bucket pair capacity
constexpr int TILE_A = 4096;
constexpr int NB_A = (ETOT + TILE_A - 1) / TILE_A; // 333

// ---- bf16 helpers (RNE) ----
__device__ __forceinline__ unsigned short f2b(float f) {
  unsigned u = __builtin_bit_cast(unsigned, f);
  u += 0x7FFFu + ((u >> 16) & 1u);
  return (unsigned short)(u >> 16);
}
__device__ __forceinline__ unsigned pk2(float lo, float hi) {
  return (unsigned)f2b(lo) | ((unsigned)f2b(hi) << 16);
}
__device__ __forceinline__ float b2f_lo(unsigned u) {
  return __builtin_bit_cast(float, u << 16);
}
__device__ __forceinline__ float b2f_hi(unsigned u) {
  return __builtin_bit_cast(float, u & 0xFFFF0000u);
}

// ---------------------------------------------------------------------------
// prep: f2b convert of x (4.8M x 8 floats) + weight repack (221184 items)
//       + gcnt zeroing, all in one grid-stride launch.
// ---------------------------------------------------------------------------
__device__ __forceinline__ void pack_one(const float* __restrict__ Ws,
                                         const float* __restrict__ Wn,
                                         unsigned short* __restrict__ out,
                                         int t, int KS, int N, int NKT) {
  int j = t & 7, lane = (t >> 3) & 63;
  int kt = (t >> 9) % NKT, nt = t / (NKT << 9);
  int k = kt * 32 + (lane >> 4) * 8 + j;
  int n = nt * 16 + (lane & 15);
  float v = 0.f;
  if (n < N) v = (k < KS) ? Ws[k * N + n] : Wn[(k - KS) * N + n];
  out[t] = f2b(v);
}

__global__ __launch_bounds__(256)
void prep_kernel(const float4* __restrict__ x, uint4* __restrict__ xb,
                 const float* __restrict__ Ws0, const float* __restrict__ Wn0,
                 const float* __restrict__ Ws1, const float* __restrict__ Wn1,
                 const float* __restrict__ Ws2, const float* __restrict__ Wn2,
                 unsigned short* __restrict__ Wp0, unsigned short* __restrict__ Wp1,
                 unsigned short* __restrict__ Wp2, int* __restrict__ gcnt) {
  constexpr int NF = 4800000;            // f2b items (8 floats each)
  constexpr int T0 = 16 * 8 * 512;       // 65536
  constexpr int T1 = 16 * 16 * 512;      // 131072
  constexpr int T2 = 3 * 16 * 512;       // 24576
  constexpr int TOT = NF + T0 + T1 + T2;
  if (blockIdx.x == 0 && threadIdx.x < BKT) gcnt[threadIdx.x] = 0;
  int stride = gridDim.x * blockDim.x;
  for (int i = blockIdx.x * blockDim.x + threadIdx.x; i < TOT; i += stride) {
    if (i < NF) {
      float4 a = x[2 * i], b = x[2 * i + 1];
      uint4 o;
      o.x = pk2(a.x, a.y); o.y = pk2(a.z, a.w);
      o.z = pk2(b.x, b.y); o.w = pk2(b.z, b.w);
      xb[i] = o;
    } else {
      int t = i - NF;
      if (t < T0)           pack_one(Ws0, Wn0, Wp0, t, 128, 256, 8);
      else if (t < T0 + T1) pack_one(Ws1, Wn1, Wp1, t - T0, 256, 256, 16);
      else                  pack_one(Ws2, Wn2, Wp2, t - T0 - T1, 256, 47, 16);
    }
  }
}

// ---------------------------------------------------------------------------
// Binned CSR build, pass A (per-block LDS histogram + chunk reservation).
// ---------------------------------------------------------------------------
__device__ __forceinline__ void edge_at(int i,
    const int* __restrict__ s0, const int* __restrict__ d0,
    const int* __restrict__ s1, const int* __restrict__ d1,
    const int* __restrict__ s2, const int* __restrict__ d2,
    int& s, int& g) {
  if (i < E0)           { g = d0[i];                     s = s0[i]; }
  else if (i < E0 + E1) { g = N_DST0 + d1[i - E0];       s = s1[i - E0]; }
  else                  { g = N_DST0 + N_DST1 + d2[i - E0 - E1]; s = s2[i - E0 - E1]; }
}

__global__ __launch_bounds__(256)
void binA(const int* __restrict__ s0, const int* __restrict__ d0,
          const int* __restrict__ s1, const int* __restrict__ d1,
          const int* __restrict__ s2, const int* __restrict__ d2,
          int* __restrict__ gcnt, uint2* __restrict__ pairs) {
  __shared__ int lhist[BKT];
  __shared__ int lbase[BKT];
  const int t = threadIdx.x;
  lhist[t] = 0;
  __syncthreads();
  const int base = blockIdx.x * TILE_A;
  int r[16];
#pragma unroll
  for (int j = 0; j < 16; ++j) {
    int i = base + j * 256 + t;
    r[j] = -1;
    if (i < ETOT) {
      int s, g;
      edge_at(i, s0, d0, s1, d1, s2, d2, s, g);
      r[j] = atomicAdd(&lhist[g >> 9], 1);
    }
  }
  __syncthreads();
  {
    int n = lhist[t];
    lbase[t] = (n > 0) ? atomicAdd(&gcnt[t], n) : 0;
  }
  __syncthreads();
#pragma unroll
  for (int j = 0; j < 16; ++j) {
    int i = base + j * 256 + t;
    if (i < ETOT) {
      int s, g;
      edge_at(i, s0, d0, s1, d1, s2, d2, s, g);
      int b = g >> 9;
      int rel = lbase[b] + r[j];
      if (rel < CAP)
        pairs[(long long)b * CAP + rel] = make_uint2((unsigned)s, (unsigned)g);
    }
  }
}

// ---------------------------------------------------------------------------
// Pass B (absorbs the 256-wide bucket-base scan): one block per bucket.
// LDS scan of gcnt -> bucket base; 512-row histogram -> LDS scan ->
// row_end (coalesced) -> place eidx via LDS cursors.
// ---------------------------------------------------------------------------
__global__ __launch_bounds__(256)
void binB(const uint2* __restrict__ pairs, const int* __restrict__ gcnt,
          int* __restrict__ eidx, int* __restrict__ row_end) {
  __shared__ int sg[BKT];
  __shared__ int hist[512];
  __shared__ int excl[512];
  __shared__ int cur[512];
  const int b = blockIdx.x;
  const int t = threadIdx.x;
  // bucket base via redundant per-block scan of gcnt[256]
  sg[t] = gcnt[t];
  __syncthreads();
  for (int off = 1; off < 256; off <<= 1) {
    int v = (t >= off) ? sg[t - off] : 0;
    __syncthreads();
    sg[t] += v;
    __syncthreads();
  }
  const int gb = (b == 0) ? 0 : sg[b - 1];
  const int n = min(gcnt[b], CAP);
  hist[t] = 0; hist[t + 256] = 0;
  __syncthreads();
  const uint2* pb = pairs + (long long)b * CAP;
  for (int i = t; i < n; i += 256)
    atomicAdd(&hist[pb[i].y & 511], 1);
  __syncthreads();
  int h0 = hist[2 * t], h1 = hist[2 * t + 1];
  int s = h0 + h1;
  cur[t] = s;
  __syncthreads();
  for (int off = 1; off < 256; off <<= 1) {
    int v = (t >= off) ? cur[t - off] : 0;
    __syncthreads();
    cur[t] += v;
    __syncthreads();
  }
  int ex = cur[t] - s;
  excl[2 * t] = ex;
  excl[2 * t + 1] = ex + h0;
  __syncthreads();
  cur[t] = excl[t];
  cur[t + 256] = excl[t + 256];
  const int g0 = (b << 9) + t, g1 = (b << 9) + t + 256;
  if (g0 < NCNT) row_end[g0] = gb + excl[t] + hist[t];
  if (g1 < NCNT) row_end[g1] = gb + excl[t + 256] + hist[t + 256];
  __syncthreads();
  for (int i = t; i < n; i += 256) {
    uint2 p = pb[i];
    int pos = gb + atomicAdd(&cur[p.y & 511], 1);
    eidx[pos] = (int)p.x;
  }
}

// ---------------------------------------------------------------------------
// Fused SAGE layer: block = 4 waves = 32 dst rows.
// Phase 1: gather-mean of neighbors into LDS agg[32][KN+8] (bf16, padded).
// Phase 2: MFMA GEMM, self A-frags from global, neigh A-frags from LDS,
//          packed W streamed; waves split the n-tiles.
// A-frag k-map == pack k-map (k-permutation safe); C/D map m89-verified.
// ---------------------------------------------------------------------------
template <int KS, int KN, int NP, int NOUT, bool RELU, bool OUT_BF16, int FIRST>
__global__ __launch_bounds__(256)
void sage_layer(const unsigned short* __restrict__ hsrc,
                const int* __restrict__ cend,
                const int* __restrict__ eidx,
                const unsigned short* __restrict__ Wp,
                const float* __restrict__ bias,
                void* __restrict__ Cout, int M) {
  constexpr int NK = (KS + KN) / 32, NT = NP / 16;
  constexpr int PAD = KN + 8;            // row stride in bf16; %8==0 keeps 16B align
  constexpr int GRP = KN / 8;            // lanes per row slice (16B each)
  constexpr int NSUB = 64 / GRP;
  constexpr int NPW = (NT + 3) / 4;      // n-tiles per wave
  __shared__ unsigned short agg[32][PAD];

  const int t = threadIdx.x;
  const int wv = t >> 6;
  const int lane = t & 63;
  const int m0 = blockIdx.x * 32;

  // ---- phase 1: gather 8 rows per wave ----
  {
    const int sub = lane / GRP;
    const int li = lane % GRP;
    const unsigned short* hp = hsrc + li * 8;
    for (int rr = 0; rr < 8; ++rr) {
      const int r = wv * 8 + rr;
      const int w = m0 + r;
      const int beg = (FIRST && w == 0) ? 0 : cend[w - 1];
      const int end = cend[w];
      float acc[8] = {};
      int e = beg + sub;
      for (; e + NSUB < end; e += 2 * NSUB) {
        uint4 u0 = *(const uint4*)(hp + (long long)eidx[e] * KN);
        uint4 u1 = *(const uint4*)(hp + (long long)eidx[e + NSUB] * KN);
        acc[0] += b2f_lo(u0.x); acc[1] += b2f_hi(u0.x);
        acc[2] += b2f_lo(u0.y); acc[3] += b2f_hi(u0.y);
        acc[4] += b2f_lo(u0.z); acc[5] += b2f_hi(u0.z);
        acc[6] += b2f_lo(u0.w); acc[7] += b2f_hi(u0.w);
        acc[0] += b2f_lo(u1.x); acc[1] += b2f_hi(u1.x);
        acc[2] += b2f_lo(u1.y); acc[3] += b2f_hi(u1.y);
        acc[4] += b2f_lo(u1.z); acc[5] += b2f_hi(u1.z);
        acc[6] += b2f_lo(u1.w); acc[7] += b2f_hi(u1.w);
      }
      if (e < end) {
        uint4 u = *(const uint4*)(hp + (long long)eidx[e] * KN);
        acc[0] += b2f_lo(u.x); acc[1] += b2f_hi(u.x);
        acc[2] += b2f_lo(u.y); acc[3] += b2f_hi(u.y);
        acc[4] += b2f_lo(u.z); acc[5] += b2f_hi(u.z);
        acc[6] += b2f_lo(u.w); acc[7] += b2f_hi(u.w);
      }
#pragma unroll
      for (int off = GRP; off < 64; off <<= 1)
#pragma unroll
        for (int j = 0; j < 8; ++j) acc[j] += __shfl_xor(acc[j], off);
      if (sub == 0) {
        const float inv = 1.f / fmaxf((float)(end - beg), 1.f);
        uint4 o;
        o.x = pk2(acc[0] * inv, acc[1] * inv);
        o.y = pk2(acc[2] * inv, acc[3] * inv);
        o.z = pk2(acc[4] * inv, acc[5] * inv);
        o.w = pk2(acc[6] * inv, acc[7] * inv);
        *(uint4*)(&agg[r][li * 8]) = o;
      }
    }
  }
  __syncthreads();

  // ---- phase 2: GEMM on the 32 rows; waves split n-tiles ----
  const int g = lane >> 4, mi = lane & 15;
  bf16x8 a[2][NK];
#pragma unroll
  for (int s = 0; s < 2; ++s) {
    const int row16 = s * 16 + mi;
    const long long grow = m0 + row16;
#pragma unroll
    for (int kt = 0; kt < NK; ++kt) {
      const int k = kt * 32 + g * 8;
      if (kt * 32 < KS)
        a[s][kt] = *reinterpret_cast<const bf16x8*>(hsrc + grow * KS + k);
      else
        a[s][kt] = *reinterpret_cast<const bf16x8*>(&agg[row16][k - KS]);
    }
  }
  const bf16x8* wp = reinterpret_cast<const bf16x8*>(Wp);

  auto emit = [&](int nt, int s, const f32x4& acc) {
    const int col = nt * 16 + mi;
    if (col < NOUT) {
      const float bv = bias[col];
#pragma unroll
      for (int j = 0; j < 4; ++j) {
        const long long r = m0 + s * 16 + g * 4 + j;
        float v = acc[j] + bv;
        if (RELU) v = fmaxf(v, 0.f);
        if (OUT_BF16) ((unsigned short*)Cout)[r * NOUT + col] = f2b(v);
        else          ((float*)Cout)[r * NOUT + col] = v;
      }
    }
  };

  const int ntBeg = wv * NPW;
  const int ntEnd = min(ntBeg + NPW, NT);
#pragma unroll 1
  for (int nt = ntBeg; nt + 2 <= ntEnd; nt += 2) {
    f32x4 a00 = {0.f,0.f,0.f,0.f}, a01 = {0.f,0.f,0.f,0.f};
    f32x4 a10 = {0.f,0.f,0.f,0.f}, a11 = {0.f,0.f,0.f,0.f};
#pragma unroll
    for (int kt = 0; kt < NK; ++kt) {
      bf16x8 b0 = wp[(nt * NK + kt) * 64 + lane];
      bf16x8 b1 = wp[((nt + 1) * NK + kt) * 64 + lane];
      a00 = __builtin_amdgcn_mfma_f32_16x16x32_bf16(a[0][kt], b0, a00, 0, 0, 0);
      a10 = __builtin_amdgcn_mfma_f32_16x16x32_bf16(a[1][kt], b0, a10, 0, 0, 0);
      a01 = __builtin_amdgcn_mfma_f32_16x16x32_bf16(a[0][kt], b1, a01, 0, 0, 0);
      a11 = __builtin_amdgcn_mfma_f32_16x16x32_bf16(a[1][kt], b1, a11, 0, 0, 0);
    }
    emit(nt, 0, a00); emit(nt + 1, 0, a01);
    emit(nt, 1, a10); emit(nt + 1, 1, a11);
  }
  if ((ntEnd - ntBeg) & 1) {
    const int nt = ntEnd - 1;
    f32x4 a0 = {0.f,0.f,0.f,0.f}, a1 = {0.f,0.f,0.f,0.f};
#pragma unroll
    for (int kt = 0; kt < NK; ++kt) {
      bf16x8 b = wp[(nt * NK + kt) * 64 + lane];
      a0 = __builtin_amdgcn_mfma_f32_16x16x32_bf16(a[0][kt], b, a0, 0, 0, 0);
      a1 = __builtin_amdgcn_mfma_f32_16x16x32_bf16(a[1][kt], b, a1, 0, 0, 0);
    }
    emit(nt, 0, a0);
    emit(nt, 1, a1);
  }
}

extern "C" void kernel_launch(void* const* d_in, const int* in_sizes, int n_in,
                              void* d_out, int out_size, void* d_ws, size_t ws_size,
                              hipStream_t stream) {
  const float* x   = (const float*)d_in[0];
  const int* src0  = (const int*)d_in[1];
  const int* dst0  = (const int*)d_in[2];
  const int* src1  = (const int*)d_in[3];
  const int* dst1  = (const int*)d_in[4];
  const int* src2  = (const int*)d_in[5];
  const int* dst2  = (const int*)d_in[6];
  const float* Ws0 = (const float*)d_in[7];
  const float* Wn0 = (const float*)d_in[8];
  const float* b0  = (const float*)d_in[9];
  const float* Ws1 = (const float*)d_in[10];
  const float* Wn1 = (const float*)d_in[11];
  const float* b1  = (const float*)d_in[12];
  const float* Ws2 = (const float*)d_in[13];
  const float* Wn2 = (const float*)d_in[14];
  const float* b2  = (const float*)d_in[15];
  float* out = (float*)d_out;

  char* base = (char*)d_ws;
  unsigned short* xb  = (unsigned short*)base;                  // 76.8 MB
  unsigned short* h0b = (unsigned short*)(base + 76800000);     // 51.2 MB
  unsigned short* Wp0 = (unsigned short*)(base + 153600000);
  unsigned short* Wp1 = (unsigned short*)(base + 153731072);
  unsigned short* Wp2 = (unsigned short*)(base + 153993216);
  int* eidx  = (int*)(base + 154042368);                        // 5,445,760 B
  int* cnt   = (int*)(base + 159488128);                        // row_end
  int* gcnt  = (int*)(base + 159985664);

  // pairs buffer (33.6 MB) overlays h0b region: consumed by binB before
  // sage_layer L0 writes h0b.
  uint2* pairs = (uint2*)(base + 76800000);
  unsigned short* h1b = xb;   // xb dead after L0

  // ---- prep (f2b + packs + gcnt zero), then binned CSR build ----
  prep_kernel<<<2048, 256, 0, stream>>>((const float4*)x, (uint4*)xb,
      Ws0, Wn0, Ws1, Wn1, Ws2, Wn2, Wp0, Wp1, Wp2, gcnt);
  binA<<<NB_A, 256, 0, stream>>>(src0, dst0, src1, dst1, src2, dst2, gcnt, pairs);
  binB<<<NBKT_USED, 256, 0, stream>>>(pairs, gcnt, eidx, cnt);

  // ---- fused layers ----
  sage_layer<128, 128, 256, 256, true, true, 1><<<N_DST0 / 32, 256, 0, stream>>>(
      xb, cnt, eidx, Wp0, b0, h0b, N_DST0);
  sage_layer<256, 256, 256, 256, true, true, 0><<<N_DST1 / 32, 256, 0, stream>>>(
      h0b, cnt + N_DST0, eidx, Wp1, b1, h1b, N_DST1);
  sage_layer<256, 256, 48, 47, false, false, 0><<<N_DST2 / 32, 256, 0, stream>>>(
      h1b, cnt + N_DST0 + N_DST1, eidx, Wp2, b2, out, N_DST2);
}